// Round 8
// baseline (436.548 us; speedup 1.0000x reference)
//
#include <hip/hip_runtime.h>
#include <hip/hip_fp16.h>

typedef _Float16 f16x8 __attribute__((ext_vector_type(8)));
typedef float f32x4 __attribute__((ext_vector_type(4)));
typedef float f32x16 __attribute__((ext_vector_type(16)));

#define DEV __device__ __forceinline__

typedef const __attribute__((address_space(1))) void gvoid_t;
typedef __attribute__((address_space(3))) void lvoid_t;

DEV void gload16(const void* g, void* l) {
  __builtin_amdgcn_global_load_lds((gvoid_t*)g, (lvoid_t*)l, 16, 0, 0);
}

DEV f32x4 mfma16(f16x8 a, f16x8 b, f32x4 c) {
  return __builtin_amdgcn_mfma_f32_16x16x32_f16(a, b, c, 0, 0, 0);
}

DEV f32x16 mfma32(f16x8 a, f16x8 b, f32x16 c) {
  return __builtin_amdgcn_mfma_f32_32x32x16_f16(a, b, c, 0, 0, 0);
}

// ---------------- f32 -> f16 convert ----------------
__global__ __launch_bounds__(256) void cvt_kernel(const float* __restrict__ s,
                                                  __half* __restrict__ d, int n4) {
  int stride = gridDim.x * 256;
  for (int i = blockIdx.x * 256 + threadIdx.x; i < n4; i += stride) {
    float4 v = ((const float4*)s)[i];
    __align__(8) __half a[4] = {__float2half(v.x), __float2half(v.y),
                                __float2half(v.z), __float2half(v.w)};
    *((uint2*)(d + (size_t)i * 4)) = *((uint2*)a);
  }
}

// merged cvt for hs + 4 weight matrices (segment sizes hardcoded, float4 units)
__global__ __launch_bounds__(256) void cvt5_kernel(const float* __restrict__ s0,
                                                   const float* __restrict__ s1,
                                                   const float* __restrict__ s2,
                                                   const float* __restrict__ s3,
                                                   const float* __restrict__ s4,
                                                   __half* __restrict__ d0, __half* __restrict__ d1,
                                                   __half* __restrict__ d2, __half* __restrict__ d3,
                                                   __half* __restrict__ d4) {
  const int c0 = 2097152, c1 = 3670016, c2 = 4259840, c3 = 6619136, c4 = 7667712;
  int stride = gridDim.x * 256;
  for (int i = blockIdx.x * 256 + threadIdx.x; i < c4; i += stride) {
    const float* s;
    __half* d;
    int j;
    if (i < c0) { s = s0; d = d0; j = i; }
    else if (i < c1) { s = s1; d = d1; j = i - c0; }
    else if (i < c2) { s = s2; d = d2; j = i - c1; }
    else if (i < c3) { s = s3; d = d3; j = i - c2; }
    else { s = s4; d = d4; j = i - c3; }
    float4 v = ((const float4*)s)[j];
    __align__(8) __half a[4] = {__float2half(v.x), __float2half(v.y),
                                __float2half(v.z), __float2half(v.w)};
    *((uint2*)(d + (size_t)j * 4)) = *((uint2*)a);
  }
}

// ---------------- fused RMSNorm(q) + RMSNorm(kv) + k_pe RoPE ----------------
// qab row layout: [0..1535]=q_a, [1536..2047]=kv_a comp, [2048..2111]=k_pe
__global__ __launch_bounds__(256) void norm_rope_kernel(const float* __restrict__ qab,
                                                        const float* __restrict__ q_ln,
                                                        const float* __restrict__ kv_ln,
                                                        const float2* __restrict__ cs,
                                                        __half* __restrict__ qa_r,
                                                        __half* __restrict__ kv_r,
                                                        __half* __restrict__ Kb) {
  const int row = blockIdx.x, tid = threadIdx.x;
  const float* xr = qab + (size_t)row * 2112;
  float4 a0 = ((const float4*)xr)[tid];  // elems 0..1023
  float4 a1 = make_float4(0.f, 0.f, 0.f, 0.f);
  float4 b0 = make_float4(0.f, 0.f, 0.f, 0.f);
  if (tid < 128) {
    a1 = ((const float4*)xr)[256 + tid];        // 1024..1535
    b0 = ((const float4*)(xr + 1536))[tid];     // kv 0..511
  }
  float sq = a0.x * a0.x + a0.y * a0.y + a0.z * a0.z + a0.w * a0.w +
             a1.x * a1.x + a1.y * a1.y + a1.z * a1.z + a1.w * a1.w;
  float sk = b0.x * b0.x + b0.y * b0.y + b0.z * b0.z + b0.w * b0.w;
  for (int mm = 1; mm <= 32; mm <<= 1) {
    sq += __shfl_xor(sq, mm);
    sk += __shfl_xor(sk, mm);
  }
  __shared__ float r1[4], r2[4];
  __shared__ __half ro[64];
  if ((tid & 63) == 0) { r1[tid >> 6] = sq; r2[tid >> 6] = sk; }
  if (tid < 32) {
    float x0 = xr[2048 + 2 * tid], x1 = xr[2048 + 2 * tid + 1];
    float2 c = cs[row * 32 + tid];
    ro[tid] = __float2half(x0 * c.x - x1 * c.y);
    ro[32 + tid] = __float2half(x1 * c.x + x0 * c.y);
  }
  __syncthreads();
  float rsq = rsqrtf((r1[0] + r1[1] + r1[2] + r1[3]) * (1.f / 1536.f) + 1e-6f);
  float rsk = rsqrtf((r2[0] + r2[1] + r2[2] + r2[3]) * (1.f / 512.f) + 1e-6f);
  __half* yq = qa_r + (size_t)row * 1536;
  {
    int j = tid * 4;
    yq[j + 0] = __float2half(q_ln[j + 0] * a0.x * rsq);
    yq[j + 1] = __float2half(q_ln[j + 1] * a0.y * rsq);
    yq[j + 2] = __float2half(q_ln[j + 2] * a0.z * rsq);
    yq[j + 3] = __float2half(q_ln[j + 3] * a0.w * rsq);
  }
  if (tid < 128) {
    int j = 1024 + tid * 4;
    yq[j + 0] = __float2half(q_ln[j + 0] * a1.x * rsq);
    yq[j + 1] = __float2half(q_ln[j + 1] * a1.y * rsq);
    yq[j + 2] = __float2half(q_ln[j + 2] * a1.z * rsq);
    yq[j + 3] = __float2half(q_ln[j + 3] * a1.w * rsq);
    __half* yk = kv_r + (size_t)row * 512;
    int jk = tid * 4;
    yk[jk + 0] = __float2half(kv_ln[jk + 0] * b0.x * rsk);
    yk[jk + 1] = __float2half(kv_ln[jk + 1] * b0.y * rsk);
    yk[jk + 2] = __float2half(kv_ln[jk + 2] * b0.z * rsk);
    yk[jk + 3] = __float2half(kv_ln[jk + 3] * b0.w * rsk);
  }
#pragma unroll
  for (int it = 0; it < 8; ++it) {
    int i = it * 256 + tid;  // 0..2047
    int hh = i >> 6, d = i & 63;
    Kb[((size_t)hh * 2048 + row) * 192 + 128 + d] = ro[d];
  }
}

// ---------------- YaRN cos/sin table (double precision) ----------------
__global__ __launch_bounds__(256) void rope_table_kernel(const int* __restrict__ pos,
                                                         float2* __restrict__ cs) {
  int i = blockIdx.x * 256 + threadIdx.x;  // 2048*32
  int row = i >> 5, j = i & 31;
  double f = (double)j * (1.0 / 32.0);
  double fe = exp(-f * 10.81977828441028);  // BASE^-f
  double fi = fe * (1.0 / 32.0);
  double ramp = fmin(fmax(((double)j - 8.0) * (1.0 / 12.0), 0.0), 1.0);
  double inv = fi * ramp + fe * (1.0 - ramp);
  double ang = (double)pos[row] * inv;
  cs[i] = make_float2((float)cos(ang), (float)sin(ang));
}

// rope for q_pe: qpe [2048][32*64] f16 -> Q [h][row][128..191], scaled
__global__ __launch_bounds__(256) void rope_q_kernel(const __half* __restrict__ qpe,
                                                     const float2* __restrict__ cs,
                                                     __half* __restrict__ Qb, float qscale) {
  int i = blockIdx.x * 256 + threadIdx.x;  // 2048*32*32
  int row = i >> 10, rem = i & 1023, h = rem >> 5, j = rem & 31;
  float x0 = __half2float(qpe[(size_t)row * 2048 + h * 64 + 2 * j]);
  float x1 = __half2float(qpe[(size_t)row * 2048 + h * 64 + 2 * j + 1]);
  float2 c = cs[row * 32 + j];
  float o0 = (x0 * c.x - x1 * c.y) * qscale;
  float o1 = (x1 * c.x + x0 * c.y) * qscale;
  __half* dst = Qb + ((size_t)h * 2048 + row) * 192;
  dst[128 + j] = __float2half(o0);
  dst[160 + j] = __float2half(o1);
}

// ---------------- GEMM: C[M,N] = A[M,K](f16) x B[N,K](f16)^T ----------------
// 128xBN tile, BK=64, 4 waves 2x2, double-buffered LDS, 2-phase prefetch,
// XOR bank swizzle. EPI: 0=f32 store, 2=q_b split, 3=kv_b split (K nope + V^T)
template <int BN, int EPI>
__global__ __launch_bounds__(256) void gemm128(const __half* __restrict__ A, int lda,
                                               const __half* __restrict__ B, int K, int Ncols,
                                               float* __restrict__ Cf, int ldc,
                                               __half* __restrict__ O1, __half* __restrict__ O2,
                                               float qscale) {
  constexpr int NFR = BN / 32;  // B frags per wave: 4 (BN=128) or 6 (BN=192)
  __shared__ __align__(16) char As[2 * 128 * 128];
  __shared__ __align__(16) char Bs[2 * BN * 128];
  const int tid = threadIdx.x;
  const int lane = tid & 63, w = tid >> 6;
  const int l15 = lane & 15, g = lane >> 4;
  const int wr = w >> 1, wc = w & 1;
  // XCD-chunk swizzle (nwg % 8 == 0 for all launches)
  const int nwg = gridDim.x * gridDim.y;
  int wg = blockIdx.y * gridDim.x + blockIdx.x;
  wg = (wg & 7) * (nwg >> 3) + (wg >> 3);
  const int m0 = (wg / gridDim.x) * 128, n0 = (wg % gridDim.x) * BN;
  // staging geometry: chunks of 1KB (8 rows x 128B)
  const int srow = lane >> 3;                // row within chunk
  const int scol = ((lane & 7) ^ srow) * 8;  // pre-swizzled source col (halves)
  f32x4 acc[4][NFR] = {};
  const int nt = K >> 6;

  auto stage = [&](int t, int buf) {
    const __half* Ab = A + t * 64 + scol;
    const __half* Bb = B + t * 64 + scol;
#pragma unroll
    for (int cc = 0; cc < 4; ++cc) {
      int ch = w * 4 + cc;
      gload16(Ab + (size_t)(m0 + ch * 8 + srow) * lda, As + buf * 16384 + ch * 1024);
    }
#pragma unroll
    for (int cc = 0; cc < NFR; ++cc) {
      int ch = w * NFR + cc;
      gload16(Bb + (size_t)(n0 + ch * 8 + srow) * K, Bs + buf * (BN * 128) + ch * 1024);
    }
  };

  stage(0, 0);
  __syncthreads();

  for (int t = 0; t < nt; ++t) {
    const int buf = t & 1;
    if (t + 1 < nt) stage(t + 1, buf ^ 1);
    const char* Ab = As + buf * 16384;
    const char* Bb = Bs + buf * (BN * 128);
#pragma unroll
    for (int kk = 0; kk < 2; ++kk) {
      f16x8 af[4], bf[NFR];
#pragma unroll
      for (int m = 0; m < 4; ++m) {
        int r = wr * 64 + m * 16 + l15;
        af[m] = *(const f16x8*)(Ab + r * 128 + (((kk << 2) | g) ^ (r & 7)) * 16);
      }
#pragma unroll
      for (int n = 0; n < NFR; ++n) {
        int r = wc * (BN / 2) + n * 16 + l15;
        bf[n] = *(const f16x8*)(Bb + r * 128 + (((kk << 2) | g) ^ (r & 7)) * 16);
      }
#pragma unroll
      for (int m = 0; m < 4; ++m)
#pragma unroll
        for (int n = 0; n < NFR; ++n) acc[m][n] = mfma16(af[m], bf[n], acc[m][n]);
    }
    __syncthreads();  // drains stage(t+1); separates reads of buf from overwrite
  }

#pragma unroll
  for (int m = 0; m < 4; ++m)
#pragma unroll
    for (int n = 0; n < NFR; ++n)
#pragma unroll
      for (int i = 0; i < 4; ++i) {
        int row = m0 + wr * 64 + m * 16 + g * 4 + i;
        int col = n0 + wc * (BN / 2) + n * 16 + l15;
        float v = acc[m][n][i];
        if (EPI == 0) {
          if (col < Ncols) Cf[(size_t)row * ldc + col] = v;
        } else if (EPI == 2) {
          int h = col / 192, d = col - h * 192;
          if (d < 128)
            O1[((size_t)h * 2048 + row) * 192 + d] = __float2half(v * qscale);
          else
            O2[(size_t)row * 2048 + h * 64 + (d - 128)] = __float2half(v);
        } else if (EPI == 3) {
          int h = col >> 8, d = col & 255;
          if (d < 128)
            O1[((size_t)h * 2048 + row) * 192 + d] = __float2half(v);
          else
            O2[((size_t)h * 128 + (d - 128)) * 2048 + row] = __float2half(v);
        }
      }
}

// ---------------- Flash attention (32x32 MFMA, swapped ops, in-reg softmax) ----
// grid 512 blocks: h = wg>>4, qt = 15-(wg&15) (descending: long blocks first).
// QBLK=128, 4 waves x 32 q-rows; KVB=64; K,V double-buffered (80KB, 2 blocks/CU).
// S^T = mfma32(K_frag, Q_frag): lane owns q-row = q0+w*32+(lane&31); softmax is
// lane-local (31 fmax + 1 shfl_xor(32)); P packed to f16 in-reg, routed to PV's
// B-operand via shfl_xor(32); O^T = mfma32(V^T_frag, P^T_frag). One barrier/iter.
__global__ __launch_bounds__(256, 2) void attn_kernel(const __half* __restrict__ Q,
                                                      const __half* __restrict__ K,
                                                      const __half* __restrict__ Vt,
                                                      __half* __restrict__ Out) {
  __shared__ __align__(16) char Klds[2 * 64 * 384];   // 49152
  __shared__ __align__(16) char Vlds[2 * 128 * 128];  // 32768; total 81920
  int wg = blockIdx.y * gridDim.x + blockIdx.x;       // 512
  wg = (wg & 7) * 64 + (wg >> 3);
  const int h = wg >> 4, qt = 15 - (wg & 15);
  const int q0 = qt * 128;
  const int nt = 2 * qt + 2;
  const int tid = threadIdx.x, lane = tid & 63, w = tid >> 6;
  const int l31 = lane & 31, hf = lane >> 5;
  const int qrow = q0 + w * 32 + l31;           // lane's q-row (both halves same)
  const int maskT = (w < 2) ? nt - 2 : nt - 1;  // mask iter == last compute iter

  const char* Kg = (const char*)(K + (size_t)h * 2048 * 192);
  const char* Vg = (const char*)(Vt + (size_t)h * 128 * 2048);

  // K staging geometry (6 chunks/wave of 1KB; 24-slot rows, swizzled)
  int kRow[6], kSS[6];
#pragma unroll
  for (int cc = 0; cc < 6; ++cc) {
    int c = w * 6 + cc;
    int L = c * 64 + lane;
    int row = (L * 2731) >> 16;  // L/24
    int slot = L - row * 24;
    kRow[cc] = row;
    kSS[cc] = (slot & ~7) | ((slot ^ row) & 7);
  }
  // V staging geometry (4 chunks/wave; 8-slot rows, swizzled)
  int vD[4], vSS[4];
#pragma unroll
  for (int cc = 0; cc < 4; ++cc) {
    int c = w * 4 + cc;
    int L = c * 64 + lane;
    int d = L >> 3, slot = L & 7;
    vD[cc] = d;
    vSS[cc] = slot ^ (d & 7);
  }

  // Q fragments (12): B-op layout col q=l31, k-rows hf*8+j (d = dblk*16+hf*8+j)
  const __half* Qh = Q + ((size_t)h * 2048 + qrow) * 192;
  f16x8 qf[12];
#pragma unroll
  for (int dblk = 0; dblk < 12; ++dblk)
    qf[dblk] = *(const f16x8*)(Qh + dblk * 16 + hf * 8);

  f32x16 acc[4] = {};  // O^T: d = nb*32+(r&3)+8*(r>>2)+4*hf, q = l31
  float m_i = -1e30f, l_i = 0.f;

  // prologue: stage K(0),V(0) -> buf 0
#pragma unroll
  for (int cc = 0; cc < 6; ++cc)
    gload16(Kg + (size_t)kRow[cc] * 384 + kSS[cc] * 16, Klds + (w * 6 + cc) * 1024);
#pragma unroll
  for (int cc = 0; cc < 4; ++cc)
    gload16(Vg + ((size_t)vD[cc] * 2048) * 2 + vSS[cc] * 16, Vlds + (w * 4 + cc) * 1024);
  __syncthreads();

  for (int t = 0; t < nt; ++t) {
    const int kv0 = t * 64;
    if (t + 1 < nt) {  // stage next tile into other buffer
      char* Kn = Klds + ((t + 1) & 1) * 24576;
      char* Vn = Vlds + ((t + 1) & 1) * 16384;
#pragma unroll
      for (int cc = 0; cc < 6; ++cc)
        gload16(Kg + (size_t)(kv0 + 64 + kRow[cc]) * 384 + kSS[cc] * 16,
                Kn + (w * 6 + cc) * 1024);
#pragma unroll
      for (int cc = 0; cc < 4; ++cc)
        gload16(Vg + ((size_t)vD[cc] * 2048 + kv0 + 64) * 2 + vSS[cc] * 16,
                Vn + (w * 4 + cc) * 1024);
    }

    if (t <= maskT) {
      const char* Kc = Klds + (t & 1) * 24576;
      const char* Vc = Vlds + (t & 1) * 16384;
      // S^T = K x Q^T: 2 k-blocks of 32
      f32x16 sT0 = {}, sT1 = {};
#pragma unroll
      for (int dblk = 0; dblk < 12; ++dblk) {
        int row0 = l31, slot = dblk * 2 + hf;
        int ss0 = (slot & ~7) | ((slot ^ row0) & 7);
        f16x8 kf0 = *(const f16x8*)(Kc + row0 * 384 + ss0 * 16);
        sT0 = mfma32(kf0, qf[dblk], sT0);
        int row1 = 32 + l31;
        int ss1 = (slot & ~7) | ((slot ^ row1) & 7);
        f16x8 kf1 = *(const f16x8*)(Kc + row1 * 384 + ss1 * 16);
        sT1 = mfma32(kf1, qf[dblk], sT1);
      }
      float ps[32];
#pragma unroll
      for (int r = 0; r < 16; ++r) { ps[r] = sT0[r]; ps[16 + r] = sT1[r]; }
      if (t == maskT) {
#pragma unroll
        for (int kb = 0; kb < 2; ++kb)
#pragma unroll
          for (int r = 0; r < 16; ++r) {
            int kg = kv0 + kb * 32 + (r & 3) + 8 * (r >> 2) + 4 * hf;
            if (kg > qrow) ps[kb * 16 + r] = -1e30f;
          }
      }
      // lane-local row max
      float mt = ps[0];
#pragma unroll
      for (int r = 1; r < 32; ++r) mt = fmaxf(mt, ps[r]);
      mt = fmaxf(mt, __shfl_xor(mt, 32));
      float nm = fmaxf(m_i, mt);
      if (__any(mt - m_i > 8.f)) {  // defer-max (log2 domain, THR=8)
        float corr = exp2f(m_i - nm);
        m_i = nm;
        l_i *= corr;
#pragma unroll
        for (int nb = 0; nb < 4; ++nb)
#pragma unroll
          for (int r = 0; r < 16; ++r) acc[nb][r] *= corr;
      }
      // p = exp2(s - m): pack to half2 words; denominator in-register
      float rs = 0.f;
      unsigned pk[16];
#pragma unroll
      for (int r = 0; r < 16; ++r) {
        float pa = exp2f(ps[2 * r] - m_i);
        float pb = exp2f(ps[2 * r + 1] - m_i);
        rs += pa + pb;
        __half2 hh = __floats2half2_rn(pa, pb);
        pk[r] = *(unsigned*)&hh;
      }
      rs += __shfl_xor(rs, 32);
      l_i += rs;
      // PV: O^T += V^T x P^T  (B-frag assembled via cross-half shfl)
#pragma unroll
      for (int ks = 0; ks < 4; ++ks) {
        int base = (ks >> 1) * 8 + (ks & 1) * 4;
        unsigned q0u = pk[base + 0], q1u = pk[base + 1];
        unsigned q2u = pk[base + 2], q3u = pk[base + 3];
        unsigned s0 = __shfl_xor(q0u, 32), s1 = __shfl_xor(q1u, 32);
        unsigned s2 = __shfl_xor(q2u, 32), s3 = __shfl_xor(q3u, 32);
        union { f16x8 v; unsigned u[4]; } pb_;
        pb_.u[0] = hf ? s2 : q0u;
        pb_.u[1] = hf ? s3 : q1u;
        pb_.u[2] = hf ? q2u : s0;
        pb_.u[3] = hf ? q3u : s1;
#pragma unroll
        for (int nb = 0; nb < 4; ++nb) {
          int d = nb * 32 + l31;
          int ss = (ks * 2 + hf) ^ (d & 7);
          f16x8 vf = *(const f16x8*)(Vc + d * 128 + ss * 16);
          acc[nb] = mfma32(vf, pb_.v, acc[nb]);
        }
      }
    }
    __syncthreads();  // drains stage(t+1); protects buffer overwrite
  }

  float inv = 1.0f / l_i;
  __half* Or = Out + (size_t)qrow * 4096 + h * 128;
#pragma unroll
  for (int nb = 0; nb < 4; ++nb)
#pragma unroll
    for (int r2 = 0; r2 < 4; ++r2) {
      __align__(8) __half h4[4];
#pragma unroll
      for (int j = 0; j < 4; ++j) h4[j] = __float2half(acc[nb][r2 * 4 + j] * inv);
      *(uint2*)(Or + nb * 32 + r2 * 8 + hf * 4) = *(uint2*)h4;
    }
}

// ---------------- launch ----------------
extern "C" void kernel_launch(void* const* d_in, const int* in_sizes, int n_in,
                              void* d_out, int out_size, void* d_ws, size_t ws_size,
                              hipStream_t stream) {
  (void)in_sizes; (void)n_in; (void)out_size; (void)ws_size;
  const float* hs = (const float*)d_in[0];
  const int* pos = (const int*)d_in[2];
  const float* q_a_w = (const float*)d_in[3];
  const float* q_a_ln = (const float*)d_in[4];
  const float* q_b_w = (const float*)d_in[5];
  const float* kv_a_w = (const float*)d_in[6];
  const float* kv_a_ln = (const float*)d_in[7];
  const float* kv_b_w = (const float*)d_in[8];
  const float* o_w = (const float*)d_in[9];

  char* p = (char*)d_ws;
  auto alloc = [&](size_t sz) { char* r = p; p += (sz + 255) & ~(size_t)255; return r; };
  __half* hs_h = (__half*)alloc((size_t)2048 * 4096 * 2);   // later aliased as attn_out
  __half* w_qab = (__half*)alloc((size_t)2176 * 4096 * 2);  // q_a 0..1535, kv_a 1536..2111
  __half* w_qb = (__half*)alloc((size_t)6144 * 1536 * 2);
  __half* w_kvb = (__half*)alloc((size_t)8192 * 512 * 2);
  float* qab_f = (float*)alloc((size_t)2048 * 2112 * 4);    // [2048][2112]
  __half* qa_r = (__half*)alloc((size_t)2048 * 1536 * 2);
  __half* kv_r = (__half*)alloc((size_t)2048 * 512 * 2);
  float2* cs_tab = (float2*)alloc((size_t)2048 * 32 * 8);
  __half* Qb = (__half*)alloc((size_t)32 * 2048 * 192 * 2);
  __half* Kb = (__half*)alloc((size_t)32 * 2048 * 192 * 2);
  __half* Vtb = (__half*)alloc((size_t)32 * 128 * 2048 * 2);
  __half* qpe = (__half*)alloc((size_t)2048 * 2048 * 2);
  __half* attn_h = hs_h;  // alias (hs_h dead after qab GEMM)
  __half* w_o = Qb;       // alias (Q/K dead after attention)

  // 192^-0.5 * (1+0.1*ln32)^2 * log2(e)  -> scores in log2 domain
  constexpr float QSCALE = 0.13086090981960297f * 1.4426950408889634f;

  cvt5_kernel<<<2048, 256, 0, stream>>>(hs, q_a_w, kv_a_w, q_b_w, kv_b_w,
                                        hs_h, w_qab, w_qab + (size_t)1536 * 4096,
                                        w_qb, w_kvb);
  rope_table_kernel<<<(2048 * 32) / 256, 256, 0, stream>>>(pos, cs_tab);

  // combined q_a + kv_a projection: [2048,4096] x [2112,4096]^T (BN=192, 176 blocks)
  gemm128<192, 0><<<dim3(11, 16), 256, 0, stream>>>(hs_h, 4096, w_qab, 4096, 2112, qab_f,
                                                    2112, nullptr, nullptr, 1.f);
  norm_rope_kernel<<<2048, 256, 0, stream>>>(qab_f, q_a_ln, kv_a_ln, cs_tab,
                                             qa_r, kv_r, Kb);
  gemm128<128, 2><<<dim3(48, 16), 256, 0, stream>>>(qa_r, 1536, w_qb, 1536, 6144, nullptr,
                                                    0, Qb, qpe, QSCALE);
  rope_q_kernel<<<(2048 * 1024) / 256, 256, 0, stream>>>(qpe, cs_tab, Qb, QSCALE);
  gemm128<128, 3><<<dim3(64, 16), 256, 0, stream>>>(kv_r, 512, w_kvb, 512, 8192, nullptr,
                                                    0, Kb, Vtb, 1.f);
  attn_kernel<<<dim3(16, 32), 256, 0, stream>>>(Qb, Kb, Vtb, attn_h);
  cvt_kernel<<<2048, 256, 0, stream>>>(o_w, w_o, (int)((size_t)4096 * 4096 / 4));
  gemm128<128, 0><<<dim3(32, 16), 256, 0, stream>>>(attn_h, 4096, w_o, 4096, 4096,
                                                    (float*)d_out, 4096, nullptr, nullptr,
                                                    1.f);
}

// Round 9
// 426.657 us; speedup vs baseline: 1.0232x; 1.0232x over previous
//
#include <hip/hip_runtime.h>
#include <hip/hip_fp16.h>

typedef _Float16 f16x8 __attribute__((ext_vector_type(8)));
typedef float f32x4 __attribute__((ext_vector_type(4)));
typedef float f32x16 __attribute__((ext_vector_type(16)));

#define DEV __device__ __forceinline__

typedef const __attribute__((address_space(1))) void gvoid_t;
typedef __attribute__((address_space(3))) void lvoid_t;

DEV void gload16(const void* g, void* l) {
  __builtin_amdgcn_global_load_lds((gvoid_t*)g, (lvoid_t*)l, 16, 0, 0);
}

DEV f32x4 mfma16(f16x8 a, f16x8 b, f32x4 c) {
  return __builtin_amdgcn_mfma_f32_16x16x32_f16(a, b, c, 0, 0, 0);
}

DEV f32x16 mfma32(f16x8 a, f16x8 b, f32x16 c) {
  return __builtin_amdgcn_mfma_f32_32x32x16_f16(a, b, c, 0, 0, 0);
}

// ---------------- f32 -> f16 convert ----------------
__global__ __launch_bounds__(256) void cvt_kernel(const float* __restrict__ s,
                                                  __half* __restrict__ d, int n4) {
  int stride = gridDim.x * 256;
  for (int i = blockIdx.x * 256 + threadIdx.x; i < n4; i += stride) {
    float4 v = ((const float4*)s)[i];
    __align__(8) __half a[4] = {__float2half(v.x), __float2half(v.y),
                                __float2half(v.z), __float2half(v.w)};
    *((uint2*)(d + (size_t)i * 4)) = *((uint2*)a);
  }
}

// merged cvt for hs + 4 weight matrices (segment sizes hardcoded, float4 units)
__global__ __launch_bounds__(256) void cvt5_kernel(const float* __restrict__ s0,
                                                   const float* __restrict__ s1,
                                                   const float* __restrict__ s2,
                                                   const float* __restrict__ s3,
                                                   const float* __restrict__ s4,
                                                   __half* __restrict__ d0, __half* __restrict__ d1,
                                                   __half* __restrict__ d2, __half* __restrict__ d3,
                                                   __half* __restrict__ d4) {
  const int c0 = 2097152, c1 = 3670016, c2 = 4259840, c3 = 6619136, c4 = 7667712;
  int stride = gridDim.x * 256;
  for (int i = blockIdx.x * 256 + threadIdx.x; i < c4; i += stride) {
    const float* s;
    __half* d;
    int j;
    if (i < c0) { s = s0; d = d0; j = i; }
    else if (i < c1) { s = s1; d = d1; j = i - c0; }
    else if (i < c2) { s = s2; d = d2; j = i - c1; }
    else if (i < c3) { s = s3; d = d3; j = i - c2; }
    else { s = s4; d = d4; j = i - c3; }
    float4 v = ((const float4*)s)[j];
    __align__(8) __half a[4] = {__float2half(v.x), __float2half(v.y),
                                __float2half(v.z), __float2half(v.w)};
    *((uint2*)(d + (size_t)j * 4)) = *((uint2*)a);
  }
}

// ---------------- fused RMSNorm(q) + RMSNorm(kv) + k_pe RoPE ----------------
// qab row layout: [0..1535]=q_a, [1536..2047]=kv_a comp, [2048..2111]=k_pe
__global__ __launch_bounds__(256) void norm_rope_kernel(const float* __restrict__ qab,
                                                        const float* __restrict__ q_ln,
                                                        const float* __restrict__ kv_ln,
                                                        const float2* __restrict__ cs,
                                                        __half* __restrict__ qa_r,
                                                        __half* __restrict__ kv_r,
                                                        __half* __restrict__ Kb) {
  const int row = blockIdx.x, tid = threadIdx.x;
  const float* xr = qab + (size_t)row * 2112;
  float4 a0 = ((const float4*)xr)[tid];  // elems 0..1023
  float4 a1 = make_float4(0.f, 0.f, 0.f, 0.f);
  float4 b0 = make_float4(0.f, 0.f, 0.f, 0.f);
  if (tid < 128) {
    a1 = ((const float4*)xr)[256 + tid];        // 1024..1535
    b0 = ((const float4*)(xr + 1536))[tid];     // kv 0..511
  }
  float sq = a0.x * a0.x + a0.y * a0.y + a0.z * a0.z + a0.w * a0.w +
             a1.x * a1.x + a1.y * a1.y + a1.z * a1.z + a1.w * a1.w;
  float sk = b0.x * b0.x + b0.y * b0.y + b0.z * b0.z + b0.w * b0.w;
  for (int mm = 1; mm <= 32; mm <<= 1) {
    sq += __shfl_xor(sq, mm);
    sk += __shfl_xor(sk, mm);
  }
  __shared__ float r1[4], r2[4];
  __shared__ __half ro[64];
  if ((tid & 63) == 0) { r1[tid >> 6] = sq; r2[tid >> 6] = sk; }
  if (tid < 32) {
    float x0 = xr[2048 + 2 * tid], x1 = xr[2048 + 2 * tid + 1];
    float2 c = cs[row * 32 + tid];
    ro[tid] = __float2half(x0 * c.x - x1 * c.y);
    ro[32 + tid] = __float2half(x1 * c.x + x0 * c.y);
  }
  __syncthreads();
  float rsq = rsqrtf((r1[0] + r1[1] + r1[2] + r1[3]) * (1.f / 1536.f) + 1e-6f);
  float rsk = rsqrtf((r2[0] + r2[1] + r2[2] + r2[3]) * (1.f / 512.f) + 1e-6f);
  __half* yq = qa_r + (size_t)row * 1536;
  {
    int j = tid * 4;
    yq[j + 0] = __float2half(q_ln[j + 0] * a0.x * rsq);
    yq[j + 1] = __float2half(q_ln[j + 1] * a0.y * rsq);
    yq[j + 2] = __float2half(q_ln[j + 2] * a0.z * rsq);
    yq[j + 3] = __float2half(q_ln[j + 3] * a0.w * rsq);
  }
  if (tid < 128) {
    int j = 1024 + tid * 4;
    yq[j + 0] = __float2half(q_ln[j + 0] * a1.x * rsq);
    yq[j + 1] = __float2half(q_ln[j + 1] * a1.y * rsq);
    yq[j + 2] = __float2half(q_ln[j + 2] * a1.z * rsq);
    yq[j + 3] = __float2half(q_ln[j + 3] * a1.w * rsq);
    __half* yk = kv_r + (size_t)row * 512;
    int jk = tid * 4;
    yk[jk + 0] = __float2half(kv_ln[jk + 0] * b0.x * rsk);
    yk[jk + 1] = __float2half(kv_ln[jk + 1] * b0.y * rsk);
    yk[jk + 2] = __float2half(kv_ln[jk + 2] * b0.z * rsk);
    yk[jk + 3] = __float2half(kv_ln[jk + 3] * b0.w * rsk);
  }
#pragma unroll
  for (int it = 0; it < 8; ++it) {
    int i = it * 256 + tid;  // 0..2047
    int hh = i >> 6, d = i & 63;
    Kb[((size_t)hh * 2048 + row) * 192 + 128 + d] = ro[d];
  }
}

// ---------------- YaRN cos/sin table (double precision) ----------------
__global__ __launch_bounds__(256) void rope_table_kernel(const int* __restrict__ pos,
                                                         float2* __restrict__ cs) {
  int i = blockIdx.x * 256 + threadIdx.x;  // 2048*32
  int row = i >> 5, j = i & 31;
  double f = (double)j * (1.0 / 32.0);
  double fe = exp(-f * 10.81977828441028);  // BASE^-f
  double fi = fe * (1.0 / 32.0);
  double ramp = fmin(fmax(((double)j - 8.0) * (1.0 / 12.0), 0.0), 1.0);
  double inv = fi * ramp + fe * (1.0 - ramp);
  double ang = (double)pos[row] * inv;
  cs[i] = make_float2((float)cos(ang), (float)sin(ang));
}

// rope for q_pe: qpe [2048][32*64] f16 -> Q [h][row][128..191], scaled
__global__ __launch_bounds__(256) void rope_q_kernel(const __half* __restrict__ qpe,
                                                     const float2* __restrict__ cs,
                                                     __half* __restrict__ Qb, float qscale) {
  int i = blockIdx.x * 256 + threadIdx.x;  // 2048*32*32
  int row = i >> 10, rem = i & 1023, h = rem >> 5, j = rem & 31;
  float x0 = __half2float(qpe[(size_t)row * 2048 + h * 64 + 2 * j]);
  float x1 = __half2float(qpe[(size_t)row * 2048 + h * 64 + 2 * j + 1]);
  float2 c = cs[row * 32 + j];
  float o0 = (x0 * c.x - x1 * c.y) * qscale;
  float o1 = (x1 * c.x + x0 * c.y) * qscale;
  __half* dst = Qb + ((size_t)h * 2048 + row) * 192;
  dst[128 + j] = __float2half(o0);
  dst[160 + j] = __float2half(o1);
}

// ---------------- GEMM: C[M,N] = A[M,K](f16) x B[N,K](f16)^T ----------------
// 128xBN tile, BK=64, 4 waves 2x2, double-buffered LDS, 2-phase prefetch,
// XOR bank swizzle. EPI: 0=f32 store, 2=q_b split, 3=kv_b split (K nope + V^T)
template <int BN, int EPI>
__global__ __launch_bounds__(256) void gemm128(const __half* __restrict__ A, int lda,
                                               const __half* __restrict__ B, int K, int Ncols,
                                               float* __restrict__ Cf, int ldc,
                                               __half* __restrict__ O1, __half* __restrict__ O2,
                                               float qscale) {
  constexpr int NFR = BN / 32;  // B frags per wave: 4 (BN=128) or 6 (BN=192)
  __shared__ __align__(16) char As[2 * 128 * 128];
  __shared__ __align__(16) char Bs[2 * BN * 128];
  const int tid = threadIdx.x;
  const int lane = tid & 63, w = tid >> 6;
  const int l15 = lane & 15, g = lane >> 4;
  const int wr = w >> 1, wc = w & 1;
  // XCD-chunk swizzle (nwg % 8 == 0 for all launches)
  const int nwg = gridDim.x * gridDim.y;
  int wg = blockIdx.y * gridDim.x + blockIdx.x;
  wg = (wg & 7) * (nwg >> 3) + (wg >> 3);
  const int m0 = (wg / gridDim.x) * 128, n0 = (wg % gridDim.x) * BN;
  // staging geometry: chunks of 1KB (8 rows x 128B)
  const int srow = lane >> 3;                // row within chunk
  const int scol = ((lane & 7) ^ srow) * 8;  // pre-swizzled source col (halves)
  f32x4 acc[4][NFR] = {};
  const int nt = K >> 6;

  auto stage = [&](int t, int buf) {
    const __half* Ab = A + t * 64 + scol;
    const __half* Bb = B + t * 64 + scol;
#pragma unroll
    for (int cc = 0; cc < 4; ++cc) {
      int ch = w * 4 + cc;
      gload16(Ab + (size_t)(m0 + ch * 8 + srow) * lda, As + buf * 16384 + ch * 1024);
    }
#pragma unroll
    for (int cc = 0; cc < NFR; ++cc) {
      int ch = w * NFR + cc;
      gload16(Bb + (size_t)(n0 + ch * 8 + srow) * K, Bs + buf * (BN * 128) + ch * 1024);
    }
  };

  stage(0, 0);
  __syncthreads();

  for (int t = 0; t < nt; ++t) {
    const int buf = t & 1;
    if (t + 1 < nt) stage(t + 1, buf ^ 1);
    const char* Ab = As + buf * 16384;
    const char* Bb = Bs + buf * (BN * 128);
#pragma unroll
    for (int kk = 0; kk < 2; ++kk) {
      f16x8 af[4], bf[NFR];
#pragma unroll
      for (int m = 0; m < 4; ++m) {
        int r = wr * 64 + m * 16 + l15;
        af[m] = *(const f16x8*)(Ab + r * 128 + (((kk << 2) | g) ^ (r & 7)) * 16);
      }
#pragma unroll
      for (int n = 0; n < NFR; ++n) {
        int r = wc * (BN / 2) + n * 16 + l15;
        bf[n] = *(const f16x8*)(Bb + r * 128 + (((kk << 2) | g) ^ (r & 7)) * 16);
      }
#pragma unroll
      for (int m = 0; m < 4; ++m)
#pragma unroll
        for (int n = 0; n < NFR; ++n) acc[m][n] = mfma16(af[m], bf[n], acc[m][n]);
    }
    __syncthreads();  // drains stage(t+1); separates reads of buf from overwrite
  }

#pragma unroll
  for (int m = 0; m < 4; ++m)
#pragma unroll
    for (int n = 0; n < NFR; ++n)
#pragma unroll
      for (int i = 0; i < 4; ++i) {
        int row = m0 + wr * 64 + m * 16 + g * 4 + i;
        int col = n0 + wc * (BN / 2) + n * 16 + l15;
        float v = acc[m][n][i];
        if (EPI == 0) {
          if (col < Ncols) Cf[(size_t)row * ldc + col] = v;
        } else if (EPI == 2) {
          int h = col / 192, d = col - h * 192;
          if (d < 128)
            O1[((size_t)h * 2048 + row) * 192 + d] = __float2half(v * qscale);
          else
            O2[(size_t)row * 2048 + h * 64 + (d - 128)] = __float2half(v);
        } else if (EPI == 3) {
          int h = col >> 8, d = col & 255;
          if (d < 128)
            O1[((size_t)h * 2048 + row) * 192 + d] = __float2half(v);
          else
            O2[((size_t)h * 128 + (d - 128)) * 2048 + row] = __float2half(v);
        }
      }
}

// ---------------- Flash attention (32x32 MFMA, in-reg softmax, uniform pairing) --
// grid dim3(8,32) = 256 blocks, 1 block/CU (LDS 80KB): wg = by*8+bx; h = wg&31,
// qtA = wg>>5 (0..7). Block does q-tiles qtA and 15-qtA in sequence -> exactly
// 36 KV-iters per block (uniform, zero drain). XCD = wg&7 -> 4 heads/XCD.
// 4 waves x 32 q-rows (QBLK=128); KVB=64; K,V double-buffered, 1 barrier/iter.
// S^T = mfma32(K,Q): lane owns q-row; softmax lane-local; P exchanged via
// shfl_xor(32) to PV B-operand; O^T = mfma32(V^T, P^T).
__global__ __launch_bounds__(256) void attn_kernel(const __half* __restrict__ Q,
                                                   const __half* __restrict__ K,
                                                   const __half* __restrict__ Vt,
                                                   __half* __restrict__ Out) {
  __shared__ __align__(16) char Klds[2 * 64 * 384];   // 49152
  __shared__ __align__(16) char Vlds[2 * 128 * 128];  // 32768; total 81920 -> 1 blk/CU
  const int wg = blockIdx.y * gridDim.x + blockIdx.x;  // 0..255
  const int h = wg & 31, qtA = wg >> 5;                // qtA 0..7
  const int tid = threadIdx.x, lane = tid & 63, w = tid >> 6;
  const int l31 = lane & 31, hf = lane >> 5;

  const char* Kg = (const char*)(K + (size_t)h * 2048 * 192);
  const char* Vg = (const char*)(Vt + (size_t)h * 128 * 2048);

  // K staging geometry (6 chunks/wave of 1KB; 24-slot rows, swizzled)
  int kRow[6], kSS[6];
#pragma unroll
  for (int cc = 0; cc < 6; ++cc) {
    int c = w * 6 + cc;
    int L = c * 64 + lane;
    int row = (L * 2731) >> 16;  // L/24
    int slot = L - row * 24;
    kRow[cc] = row;
    kSS[cc] = (slot & ~7) | ((slot ^ row) & 7);
  }
  // V staging geometry (4 chunks/wave; 8-slot rows, swizzled)
  int vD[4], vSS[4];
#pragma unroll
  for (int cc = 0; cc < 4; ++cc) {
    int c = w * 4 + cc;
    int L = c * 64 + lane;
    int d = L >> 3, slot = L & 7;
    vD[cc] = d;
    vSS[cc] = slot ^ (d & 7);
  }

  for (int ht = 0; ht < 2; ++ht) {
    const int qt = ht ? (15 - qtA) : qtA;
    const int q0 = qt * 128;
    const int nt = 2 * qt + 2;
    const int qrow = q0 + w * 32 + l31;           // lane's q-row
    const int maskT = (w < 2) ? nt - 2 : nt - 1;  // mask iter == last compute iter

    // Q fragments (12): B-op layout col q=l31, k-rows hf*8+j (d = dblk*16+hf*8+j)
    const __half* Qh = Q + ((size_t)h * 2048 + qrow) * 192;
    f16x8 qf[12];
#pragma unroll
    for (int dblk = 0; dblk < 12; ++dblk)
      qf[dblk] = *(const f16x8*)(Qh + dblk * 16 + hf * 8);

    f32x16 acc[4] = {};  // O^T: d = nb*32+(r&3)+8*(r>>2)+4*hf, q = l31
    float m_i = -1e30f, l_i = 0.f;

    // prologue: stage K(0),V(0) -> buf 0 (prior phase's end barrier protects)
#pragma unroll
    for (int cc = 0; cc < 6; ++cc)
      gload16(Kg + (size_t)kRow[cc] * 384 + kSS[cc] * 16, Klds + (w * 6 + cc) * 1024);
#pragma unroll
    for (int cc = 0; cc < 4; ++cc)
      gload16(Vg + ((size_t)vD[cc] * 2048) * 2 + vSS[cc] * 16, Vlds + (w * 4 + cc) * 1024);
    __syncthreads();

    for (int t = 0; t < nt; ++t) {
      const int kv0 = t * 64;
      if (t + 1 < nt) {  // stage next tile into other buffer
        char* Kn = Klds + ((t + 1) & 1) * 24576;
        char* Vn = Vlds + ((t + 1) & 1) * 16384;
#pragma unroll
        for (int cc = 0; cc < 6; ++cc)
          gload16(Kg + (size_t)(kv0 + 64 + kRow[cc]) * 384 + kSS[cc] * 16,
                  Kn + (w * 6 + cc) * 1024);
#pragma unroll
        for (int cc = 0; cc < 4; ++cc)
          gload16(Vg + ((size_t)vD[cc] * 2048 + kv0 + 64) * 2 + vSS[cc] * 16,
                  Vn + (w * 4 + cc) * 1024);
      }

      if (t <= maskT) {
        const char* Kc = Klds + (t & 1) * 24576;
        const char* Vc = Vlds + (t & 1) * 16384;
        // S^T = K x Q^T: 2 k-blocks of 32
        f32x16 sT0 = {}, sT1 = {};
#pragma unroll
        for (int dblk = 0; dblk < 12; ++dblk) {
          int row0 = l31, slot = dblk * 2 + hf;
          int ss0 = (slot & ~7) | ((slot ^ row0) & 7);
          f16x8 kf0 = *(const f16x8*)(Kc + row0 * 384 + ss0 * 16);
          sT0 = mfma32(kf0, qf[dblk], sT0);
          int row1 = 32 + l31;
          int ss1 = (slot & ~7) | ((slot ^ row1) & 7);
          f16x8 kf1 = *(const f16x8*)(Kc + row1 * 384 + ss1 * 16);
          sT1 = mfma32(kf1, qf[dblk], sT1);
        }
        float ps[32];
#pragma unroll
        for (int r = 0; r < 16; ++r) { ps[r] = sT0[r]; ps[16 + r] = sT1[r]; }
        if (t == maskT) {
#pragma unroll
          for (int kb = 0; kb < 2; ++kb)
#pragma unroll
            for (int r = 0; r < 16; ++r) {
              int kg = kv0 + kb * 32 + (r & 3) + 8 * (r >> 2) + 4 * hf;
              if (kg > qrow) ps[kb * 16 + r] = -1e30f;
            }
        }
        // lane-local row max
        float mt = ps[0];
#pragma unroll
        for (int r = 1; r < 32; ++r) mt = fmaxf(mt, ps[r]);
        mt = fmaxf(mt, __shfl_xor(mt, 32));
        float nm = fmaxf(m_i, mt);
        if (__any(mt - m_i > 8.f)) {  // defer-max (log2 domain, THR=8)
          float corr = exp2f(m_i - nm);
          m_i = nm;
          l_i *= corr;
#pragma unroll
          for (int nb = 0; nb < 4; ++nb)
#pragma unroll
            for (int r = 0; r < 16; ++r) acc[nb][r] *= corr;
        }
        // p = exp2(s - m): pack to half2 words; denominator in-register
        float rs = 0.f;
        unsigned pk[16];
#pragma unroll
        for (int r = 0; r < 16; ++r) {
          float pa = exp2f(ps[2 * r] - m_i);
          float pb = exp2f(ps[2 * r + 1] - m_i);
          rs += pa + pb;
          __half2 hh = __floats2half2_rn(pa, pb);
          pk[r] = *(unsigned*)&hh;
        }
        rs += __shfl_xor(rs, 32);
        l_i += rs;
        // PV: O^T += V^T x P^T  (B-frag assembled via cross-half shfl)
#pragma unroll
        for (int ks = 0; ks < 4; ++ks) {
          int base = (ks >> 1) * 8 + (ks & 1) * 4;
          unsigned q0u = pk[base + 0], q1u = pk[base + 1];
          unsigned q2u = pk[base + 2], q3u = pk[base + 3];
          unsigned s0 = __shfl_xor(q0u, 32), s1 = __shfl_xor(q1u, 32);
          unsigned s2 = __shfl_xor(q2u, 32), s3 = __shfl_xor(q3u, 32);
          union { f16x8 v; unsigned u[4]; } pb_;
          pb_.u[0] = hf ? s2 : q0u;
          pb_.u[1] = hf ? s3 : q1u;
          pb_.u[2] = hf ? q2u : s0;
          pb_.u[3] = hf ? q3u : s1;
#pragma unroll
          for (int nb = 0; nb < 4; ++nb) {
            int d = nb * 32 + l31;
            int ss = (ks * 2 + hf) ^ (d & 7);
            f16x8 vf = *(const f16x8*)(Vc + d * 128 + ss * 16);
            acc[nb] = mfma32(vf, pb_.v, acc[nb]);
          }
        }
      }
      __syncthreads();  // drains stage(t+1); protects buffer overwrite
    }

    float inv = 1.0f / l_i;
    __half* Or = Out + (size_t)qrow * 4096 + h * 128;
#pragma unroll
    for (int nb = 0; nb < 4; ++nb)
#pragma unroll
      for (int r2 = 0; r2 < 4; ++r2) {
        __align__(8) __half h4[4];
#pragma unroll
        for (int j = 0; j < 4; ++j) h4[j] = __float2half(acc[nb][r2 * 4 + j] * inv);
        *(uint2*)(Or + nb * 32 + r2 * 8 + hf * 4) = *(uint2*)h4;
      }
  }
}

// ---------------- launch ----------------
extern "C" void kernel_launch(void* const* d_in, const int* in_sizes, int n_in,
                              void* d_out, int out_size, void* d_ws, size_t ws_size,
                              hipStream_t stream) {
  (void)in_sizes; (void)n_in; (void)out_size; (void)ws_size;
  const float* hs = (const float*)d_in[0];
  const int* pos = (const int*)d_in[2];
  const float* q_a_w = (const float*)d_in[3];
  const float* q_a_ln = (const float*)d_in[4];
  const float* q_b_w = (const float*)d_in[5];
  const float* kv_a_w = (const float*)d_in[6];
  const float* kv_a_ln = (const float*)d_in[7];
  const float* kv_b_w = (const float*)d_in[8];
  const float* o_w = (const float*)d_in[9];

  char* p = (char*)d_ws;
  auto alloc = [&](size_t sz) { char* r = p; p += (sz + 255) & ~(size_t)255; return r; };
  __half* hs_h = (__half*)alloc((size_t)2048 * 4096 * 2);   // later aliased as attn_out
  __half* w_qab = (__half*)alloc((size_t)2176 * 4096 * 2);  // q_a 0..1535, kv_a 1536..2111
  __half* w_qb = (__half*)alloc((size_t)6144 * 1536 * 2);
  __half* w_kvb = (__half*)alloc((size_t)8192 * 512 * 2);
  float* qab_f = (float*)alloc((size_t)2048 * 2112 * 4);    // [2048][2112]
  __half* qa_r = (__half*)alloc((size_t)2048 * 1536 * 2);
  __half* kv_r = (__half*)alloc((size_t)2048 * 512 * 2);
  float2* cs_tab = (float2*)alloc((size_t)2048 * 32 * 8);
  __half* Qb = (__half*)alloc((size_t)32 * 2048 * 192 * 2);
  __half* Kb = (__half*)alloc((size_t)32 * 2048 * 192 * 2);
  __half* Vtb = (__half*)alloc((size_t)32 * 128 * 2048 * 2);
  __half* qpe = (__half*)alloc((size_t)2048 * 2048 * 2);
  __half* attn_h = hs_h;  // alias (hs_h dead after qab GEMM)
  __half* w_o = Qb;       // alias (Q/K dead after attention)

  // 192^-0.5 * (1+0.1*ln32)^2 * log2(e)  -> scores in log2 domain
  constexpr float QSCALE = 0.13086090981960297f * 1.4426950408889634f;

  cvt5_kernel<<<2048, 256, 0, stream>>>(hs, q_a_w, kv_a_w, q_b_w, kv_b_w,
                                        hs_h, w_qab, w_qab + (size_t)1536 * 4096,
                                        w_qb, w_kvb);
  rope_table_kernel<<<(2048 * 32) / 256, 256, 0, stream>>>(pos, cs_tab);

  // combined q_a + kv_a projection: [2048,4096] x [2112,4096]^T (BN=192, 176 blocks)
  gemm128<192, 0><<<dim3(11, 16), 256, 0, stream>>>(hs_h, 4096, w_qab, 4096, 2112, qab_f,
                                                    2112, nullptr, nullptr, 1.f);
  norm_rope_kernel<<<2048, 256, 0, stream>>>(qab_f, q_a_ln, kv_a_ln, cs_tab,
                                             qa_r, kv_r, Kb);
  gemm128<128, 2><<<dim3(48, 16), 256, 0, stream>>>(qa_r, 1536, w_qb, 1536, 6144, nullptr,
                                                    0, Qb, qpe, QSCALE);
  rope_q_kernel<<<(2048 * 1024) / 256, 256, 0, stream>>>(qpe, cs_tab, Qb, QSCALE);
  gemm128<128, 3><<<dim3(64, 16), 256, 0, stream>>>(kv_r, 512, w_kvb, 512, 8192, nullptr,
                                                    0, Kb, Vtb, 1.f);
  attn_kernel<<<dim3(8, 32), 256, 0, stream>>>(Qb, Kb, Vtb, attn_h);
  cvt_kernel<<<2048, 256, 0, stream>>>(o_w, w_o, (int)((size_t)4096 * 4096 / 4));
  gemm128<128, 0><<<dim3(32, 16), 256, 0, stream>>>(attn_h, 4096, w_o, 4096, 4096,
                                                    (float*)d_out, 4096, nullptr, nullptr,
                                                    1.f);
}